// Round 1
// baseline (238.065 us; speedup 1.0000x reference)
//
#include <hip/hip_runtime.h>
#include <hip/hip_bf16.h>
#include <stdint.h>

#define N_PTS 16384
#define C_CH  64
#define D_REF 5
#define LOG2E 1.44269504088896340736f

typedef __attribute__((ext_vector_type(8))) short bf16x8;
typedef __attribute__((ext_vector_type(4))) float f32x4;

// round-half-up fp32 -> bf16 pair pack (unbiased enough; avoids RTZ bias)
__device__ __forceinline__ unsigned pack_bf16(float lo, float hi) {
    unsigned a = __builtin_bit_cast(unsigned, lo) + 0x8000u;
    unsigned b = __builtin_bit_cast(unsigned, hi) + 0x8000u;
    // result bytes [0,1] = a bytes [2,3]; bytes [2,3] = b bytes [2,3]
    return __builtin_amdgcn_perm(b, a, 0x07060302u);
}

__device__ __forceinline__ unsigned short to_bf16(float v) {
    unsigned u = __builtin_bit_cast(unsigned, v) + 0x8000u;
    return (unsigned short)(u >> 16);
}

__device__ __forceinline__ float fast_exp2(float x) {
#if __has_builtin(__builtin_amdgcn_exp2f)
    return __builtin_amdgcn_exp2f(x);
#else
    return exp2f(x);
#endif
}

// ---------------- prep 1: U [N][64] fp32 -> Ut [64][N] bf16 -------------
__global__ __launch_bounds__(256) void prep_transpose(
    const float* __restrict__ U, unsigned short* __restrict__ Ut)
{
    __shared__ unsigned short tile[64 * 72];   // [c][j_local], pad 72
    const int t  = threadIdx.x;
    const int j0 = blockIdx.x * 64;

    const int c  = t & 63;
    const int jb = t >> 6;                     // 0..3
#pragma unroll
    for (int k = 0; k < 16; ++k) {
        const int jr = jb + k * 4;             // 0..63
        const float v = U[(size_t)(j0 + jr) * C_CH + c];   // coalesced by c
        tile[c * 72 + jr] = to_bf16(v);
    }
    __syncthreads();
    const int c2   = t >> 2;                   // 0..63
    const int part = t & 3;                    // 0..3, 16 j's each
    const uint4* src = (const uint4*)&tile[c2 * 72 + part * 16];
    uint4* dst = (uint4*)&Ut[(size_t)c2 * N_PTS + j0 + part * 16];
    dst[0] = src[0];
    dst[1] = src[1];
}

// ---------------- prep 2: sqh[p] = -0.5*log2e*sum(ref[p]^2) -------------
__global__ __launch_bounds__(256) void prep_sqh(
    const float* __restrict__ ref, float* __restrict__ sqh)
{
    const int p = blockIdx.x * 256 + threadIdx.x;
    const float* r = ref + (size_t)p * D_REF;
    float s = r[0]*r[0] + r[1]*r[1] + r[2]*r[2] + r[3]*r[3] + r[4]*r[4];
    sqh[p] = -0.5f * LOG2E * s;
}

// ---------------- main fused kernel -------------------------------------
// grid = 512 blocks: blockIdx>>2 = i-block (128 rows), blockIdx&3 = j-split
// block = 512 threads = 8 waves; wave w owns i-tile rows [w*16, w*16+16)
// Per 32-j step: lane computes its 8 scores (B-frag layout), 4 MFMAs cover
// all 64 output channels (A = Ut from LDS). acc = D[c][i] (out^T tiles).
#define LDSU_STRIDE 136                        // bf16 elems per Ut row (128+8 pad)

__global__ __launch_bounds__(512, 4) void lsh_main(
    const float* __restrict__ U, const float* __restrict__ ref,
    const unsigned short* __restrict__ Ut, const float* __restrict__ sqh,
    float* __restrict__ out)
{
    __shared__ __align__(16) unsigned short utLds[64 * LDSU_STRIDE]; // 17408 B
    __shared__ __align__(16) float refLds[128 * 8];                  //  4096 B

    const int t    = threadIdx.x;
    const int lane = t & 63;
    const int wave = t >> 6;         // 0..7
    const int li   = lane & 15;      // i offset within tile == MFMA n (col)
    const int kg   = lane >> 4;      // 0..3 == k-group

    const int ib = blockIdx.x >> 2;
    const int js = blockIdx.x & 3;

    const int i_glob = ib * 128 + wave * 16 + li;

    // per-lane query point, pre-scaled by log2e
    const float* rip = ref + (size_t)i_glob * D_REF;
    const float ri0 = rip[0] * LOG2E;
    const float ri1 = rip[1] * LOG2E;
    const float ri2 = rip[2] * LOG2E;
    const float ri3 = rip[3] * LOG2E;
    const float ri4 = rip[4] * LOG2E;
    const float hi  = sqh[i_glob];

    f32x4 acc[4];
#pragma unroll
    for (int ct = 0; ct < 4; ++ct) acc[ct] = (f32x4){0.f, 0.f, 0.f, 0.f};

    const int jbase = js * 4096;

    for (int chunk = 0; chunk < 32; ++chunk) {
        const int j0 = jbase + chunk * 128;
        __syncthreads();
        // stage Ut chunk: 64 rows x 128 bf16 (256B/row), 8 threads/row
        {
            const int c    = t >> 3;     // 0..63
            const int part = t & 7;      // 0..7, 16 bf16 (32B) each
            const uint4* g = (const uint4*)(Ut + (size_t)c * N_PTS + j0 + part * 16);
            const uint4 a = g[0];
            const uint4 b = g[1];
            uint4* d = (uint4*)&utLds[c * LDSU_STRIDE + part * 16];
            d[0] = a;
            d[1] = b;
        }
        // stage ref chunk: 128 rows {r0..r4, hj, pad, pad}
        if (t < 128) {
            const int j = j0 + t;
            const float* r = ref + (size_t)j * D_REF;
            refLds[t * 8 + 0] = r[0];
            refLds[t * 8 + 1] = r[1];
            refLds[t * 8 + 2] = r[2];
            refLds[t * 8 + 3] = r[3];
            refLds[t * 8 + 4] = r[4];
            refLds[t * 8 + 5] = sqh[j];
        }
        __syncthreads();

#pragma unroll
        for (int jstep = 0; jstep < 4; ++jstep) {
            const int jb = jstep * 32 + kg * 8;   // lane's first local j
            float s[8];
#pragma unroll
            for (int jj = 0; jj < 8; ++jj) {
                const float* rr = &refLds[(jb + jj) * 8];
                const float4 r03 = *(const float4*)rr;
                const float2 r45 = *(const float2*)(rr + 4);
                float arg = hi + r45.y;                 // hi + hj
                arg = fmaf(ri0, r03.x, arg);
                arg = fmaf(ri1, r03.y, arg);
                arg = fmaf(ri2, r03.z, arg);
                arg = fmaf(ri3, r03.w, arg);
                arg = fmaf(ri4, r45.x, arg);
                arg = fminf(arg, 0.0f);                 // exact-math d2 >= 0
                s[jj] = fast_exp2(arg);
            }
            union { unsigned u[4]; bf16x8 v; } bf;
            bf.u[0] = pack_bf16(s[0], s[1]);
            bf.u[1] = pack_bf16(s[2], s[3]);
            bf.u[2] = pack_bf16(s[4], s[5]);
            bf.u[3] = pack_bf16(s[6], s[7]);
#pragma unroll
            for (int ct = 0; ct < 4; ++ct) {
                const bf16x8 af = *(const bf16x8*)&utLds[(ct * 16 + li) * LDSU_STRIDE + jb];
                acc[ct] = __builtin_amdgcn_mfma_f32_16x16x32_bf16(af, bf.v, acc[ct], 0, 0, 0);
            }
        }
    }

    // epilogue: D[row=c][col=i]; row = kg*4 + reg within 16-c tile
#pragma unroll
    for (int ct = 0; ct < 4; ++ct) {
#pragma unroll
        for (int r = 0; r < 4; ++r) {
            const int c = ct * 16 + kg * 4 + r;
            float val = acc[ct][r];
            if (js == 0) val -= U[(size_t)i_glob * C_CH + c];
            atomicAdd(&out[(size_t)i_glob * C_CH + c], val);
        }
    }
}

extern "C" void kernel_launch(void* const* d_in, const int* in_sizes, int n_in,
                              void* d_out, int out_size, void* d_ws, size_t ws_size,
                              hipStream_t stream) {
    const float* U   = (const float*)d_in[0];
    const float* ref = (const float*)d_in[1];
    float* out = (float*)d_out;

    // workspace layout: Ut bf16 [64][16384] (2 MB) | sqh fp32 [16384] (64 KB)
    unsigned short* Ut = (unsigned short*)d_ws;
    float* sqh = (float*)((char*)d_ws + (size_t)N_PTS * C_CH * 2);

    hipMemsetAsync(d_out, 0, (size_t)out_size * sizeof(float), stream);
    prep_transpose<<<N_PTS / 64, 256, 0, stream>>>(U, Ut);
    prep_sqh<<<N_PTS / 256, 256, 0, stream>>>(ref, sqh);
    lsh_main<<<512, 512, 0, stream>>>(U, ref, Ut, sqh, out);
}